// Round 1
// baseline (103.388 us; speedup 1.0000x reference)
//
#include <hip/hip_runtime.h>
#include <math.h>

#define BB 4
#define LL 512
#define DD 128
#define TQ 8            // queries per block
#define NROW (TQ + 2)   // neighbor rows needed (window spill of 1 each side)
#define EPSV 1e-8f

__global__ __launch_bounds__(256) void additive_emission_kernel(
    const float* __restrict__ x,   // [B,L,D]
    const float* __restrict__ Wt,  // [D,D] row-major [d_in][d_out]
    const float* __restrict__ Wx,  // [D,D]
    const float* __restrict__ Wa,  // [D]
    const float* __restrict__ bh,  // [D]
    const float* __restrict__ ba,  // [1]
    float* __restrict__ out)       // [B,L,D]
{
    __shared__ float xs[NROW][DD];
    __shared__ float shq[TQ][DD];
    __shared__ float shk[NROW][DD];
    __shared__ float shbh[DD];
    __shared__ float shwa[DD];
    __shared__ float score[TQ * 3];
    __shared__ float sha[TQ][3];

    const int t = threadIdx.x;
    const int b = blockIdx.x / (LL / TQ);
    const int tile = blockIdx.x % (LL / TQ);
    const int i0 = tile * TQ;
    const int jlo = i0 - 1;   // global row index of xs[0]

    // stage bh, Wa
    if (t < DD) { shbh[t] = bh[t]; shwa[t] = Wa[t]; }
    // stage x rows [jlo, jlo+NROW)
    for (int idx = t; idx < NROW * DD; idx += 256) {
        int r = idx / DD, c = idx % DD;
        int j = jlo + r;
        xs[r][c] = (j >= 0 && j < LL) ? x[(b * LL + j) * DD + c] : 0.0f;
    }
    __syncthreads();

    // ---- GEMV: q = x@Wt (8 query rows), k = x@Wx (10 neighbor rows) ----
    const int c = t & 127;     // output column
    const int h = t >> 7;      // row-group half: 0 or 1
    const int qbase = h * 4;   // q rows handled by this half
    const int kbase = h * 5;   // k rows handled by this half

    float accq[4] = {0.f, 0.f, 0.f, 0.f};
    float acck[5] = {0.f, 0.f, 0.f, 0.f, 0.f};
    #pragma unroll 4
    for (int dp = 0; dp < DD; ++dp) {
        float wt = Wt[dp * DD + c];
        float wx = Wx[dp * DD + c];
        #pragma unroll
        for (int r = 0; r < 4; ++r) accq[r] += xs[qbase + r + 1][dp] * wt;
        #pragma unroll
        for (int r = 0; r < 5; ++r) acck[r] += xs[kbase + r][dp] * wx;
    }
    #pragma unroll
    for (int r = 0; r < 4; ++r) shq[qbase + r][c] = accq[r];
    #pragma unroll
    for (int r = 0; r < 5; ++r) shk[kbase + r][c] = acck[r];
    __syncthreads();

    // ---- scores: 24 (query, window-offset) pairs, one wave per pair ----
    const int wv = t >> 6;
    const int lane = t & 63;
    const float ba0 = ba[0];
    for (int p = wv; p < TQ * 3; p += 4) {
        int qi = p / 3, jj = p - qi * 3;
        int j = jlo + qi + jj;         // global key index
        float sum;
        if (j >= 0 && j < LL) {        // wave-uniform branch
            int r = qi + jj;           // row in xs/shk
            sum = 0.0f;
            #pragma unroll
            for (int u = 0; u < 2; ++u) {
                int d = lane + u * 64;
                sum += tanhf(shq[qi][d] + shk[r][d] + shbh[d]) * shwa[d];
            }
            #pragma unroll
            for (int off = 32; off > 0; off >>= 1)
                sum += __shfl_xor(sum, off, 64);
            sum += ba0;
        } else {
            sum = -1e30f;
        }
        if (lane == 0) score[p] = sum;
    }
    __syncthreads();

    // ---- softmax over the (≤3)-wide window ----
    if (t < TQ) {
        float s0 = score[t * 3 + 0], s1 = score[t * 3 + 1], s2 = score[t * 3 + 2];
        float m = fmaxf(s0, fmaxf(s1, s2));
        float e0 = (s0 > -1e29f) ? expf(s0 - m) : 0.0f;
        float e1 = (s1 > -1e29f) ? expf(s1 - m) : 0.0f;
        float e2 = (s2 > -1e29f) ? expf(s2 - m) : 0.0f;
        float inv = 1.0f / (e0 + e1 + e2 + EPSV);
        sha[t][0] = e0 * inv;
        sha[t][1] = e1 * inv;
        sha[t][2] = e2 * inv;
    }
    __syncthreads();

    // ---- output: out[i] = sum_j a[i][j] * x[j] ----
    for (int qi = h; qi < TQ; qi += 2) {
        float v = sha[qi][0] * xs[qi][c]
                + sha[qi][1] * xs[qi + 1][c]
                + sha[qi][2] * xs[qi + 2][c];
        out[(b * LL + i0 + qi) * DD + c] = v;
    }
}

extern "C" void kernel_launch(void* const* d_in, const int* in_sizes, int n_in,
                              void* d_out, int out_size, void* d_ws, size_t ws_size,
                              hipStream_t stream) {
    const float* x  = (const float*)d_in[0];
    const float* Wt = (const float*)d_in[1];
    const float* Wx = (const float*)d_in[2];
    const float* Wa = (const float*)d_in[3];
    const float* bh = (const float*)d_in[4];
    const float* ba = (const float*)d_in[5];
    float* out = (float*)d_out;

    dim3 grid(BB * (LL / TQ));   // 256 blocks
    additive_emission_kernel<<<grid, 256, 0, stream>>>(x, Wt, Wx, Wa, bh, ba, out);
}

// Round 2
// 70.454 us; speedup vs baseline: 1.4675x; 1.4675x over previous
//
#include <hip/hip_runtime.h>
#include <math.h>

#define BB 4
#define LL 512
#define DD 128
#define TQ 4                 // queries per block
#define NROW (TQ + 2)        // 6 staged x rows (window spill 1 each side)
#define NACC (NROW + TQ)     // 10 accumulators: rows 0..5 = k, 6..9 = q
#define EPSV 1e-8f

__device__ __forceinline__ float fast_tanh(float v) {
    float e = __expf(2.0f * v);
    return 1.0f - 2.0f / (e + 1.0f);
}

__global__ __launch_bounds__(512, 4) void additive_emission_kernel(
    const float* __restrict__ x,   // [B,L,D]
    const float* __restrict__ Wt,  // [D,D] row-major [d_in][d_out]
    const float* __restrict__ Wx,  // [D,D]
    const float* __restrict__ Wa,  // [D]
    const float* __restrict__ bh,  // [D]
    const float* __restrict__ ba,  // [1]
    float* __restrict__ out)       // [B,L,D]
{
    __shared__ float xs[NROW][DD];
    __shared__ float part[4][NACC][DD];   // split-K partials
    __shared__ float qk[NACC][DD];        // combined: 0..5 = k rows, 6..9 = q rows
    __shared__ float shbh[DD];
    __shared__ float shwa[DD];
    __shared__ float score[TQ * 3];
    __shared__ float sha[TQ][3];

    const int t = threadIdx.x;
    const int b = blockIdx.x >> 7;        // 128 tiles per batch
    const int tile = blockIdx.x & 127;
    const int i0 = tile * TQ;
    const int jlo = i0 - 1;               // global row of xs[0]

    if (t < DD) { shbh[t] = bh[t]; shwa[t] = Wa[t]; }
    // stage x rows [jlo, jlo+NROW) as float4
    if (t < NROW * (DD / 4)) {            // 192 threads
        int r = t >> 5, c4 = t & 31;
        int j = jlo + r;
        float4 v = make_float4(0.f, 0.f, 0.f, 0.f);
        if (j >= 0 && j < LL)
            v = ((const float4*)x)[(size_t)(b * LL + j) * (DD / 4) + c4];
        ((float4*)xs[r])[c4] = v;
    }
    __syncthreads();

    // ---- split-K GEMV: thread = (output col c, K-quarter s) ----
    const int c = t & 127;
    const int s = t >> 7;                 // 0..3, uniform per wave
    const int dp0 = s * 32;

    float acc[NACC];
    #pragma unroll
    for (int r = 0; r < NACC; ++r) acc[r] = 0.f;

    const float* __restrict__ wtc = Wt + c;
    const float* __restrict__ wxc = Wx + c;

    #pragma unroll 2
    for (int ch = 0; ch < 8; ++ch) {
        const int dp = dp0 + ch * 4;
        float xvv[NROW][4];
        #pragma unroll
        for (int r = 0; r < NROW; ++r) {
            float4 v = ((const float4*)xs[r])[dp >> 2];   // broadcast b128, conflict-free
            xvv[r][0] = v.x; xvv[r][1] = v.y; xvv[r][2] = v.z; xvv[r][3] = v.w;
        }
        #pragma unroll
        for (int i = 0; i < 4; ++i) {
            float wx = wxc[(size_t)(dp + i) * DD];
            float wt = wtc[(size_t)(dp + i) * DD];
            #pragma unroll
            for (int r = 0; r < NROW; ++r)          // k for all 6 rows
                acc[r] += xvv[r][i] * wx;
            #pragma unroll
            for (int qi = 0; qi < TQ; ++qi)         // q for query rows (xs 1..4)
                acc[NROW + qi] += xvv[qi + 1][i] * wt;
        }
    }
    #pragma unroll
    for (int r = 0; r < NACC; ++r) part[s][r][c] = acc[r];
    __syncthreads();

    // combine split-K partials
    for (int idx = t; idx < NACC * DD; idx += 512) {
        int r = idx >> 7, cc = idx & 127;
        qk[r][cc] = part[0][r][cc] + part[1][r][cc] + part[2][r][cc] + part[3][r][cc];
    }
    __syncthreads();

    // ---- scores: 12 (query, offset) pairs, one wave per pair ----
    const int wv = t >> 6;                // 0..7
    const int lane = t & 63;
    const float ba0 = ba[0];
    for (int p = wv; p < TQ * 3; p += 8) {
        int qi = p / 3, jj = p - qi * 3;
        int j = i0 + qi - 1 + jj;         // global key index
        float sum;
        if (j >= 0 && j < LL) {           // wave-uniform branch
            int r = qi + jj;              // key row in qk/xs
            sum = 0.0f;
            #pragma unroll
            for (int u = 0; u < 2; ++u) {
                int d = lane + u * 64;
                sum += fast_tanh(qk[NROW + qi][d] + qk[r][d] + shbh[d]) * shwa[d];
            }
            #pragma unroll
            for (int off = 32; off > 0; off >>= 1)
                sum += __shfl_xor(sum, off, 64);
            sum += ba0;
        } else {
            sum = -1e30f;
        }
        if (lane == 0) score[p] = sum;
    }
    __syncthreads();

    // ---- softmax over the (<=3)-wide window ----
    if (t < TQ) {
        float s0 = score[t * 3 + 0], s1 = score[t * 3 + 1], s2 = score[t * 3 + 2];
        float m = fmaxf(s0, fmaxf(s1, s2));
        float e0 = (s0 > -1e29f) ? __expf(s0 - m) : 0.0f;
        float e1 = (s1 > -1e29f) ? __expf(s1 - m) : 0.0f;
        float e2 = (s2 > -1e29f) ? __expf(s2 - m) : 0.0f;
        float inv = 1.0f / (e0 + e1 + e2 + EPSV);
        sha[t][0] = e0 * inv;
        sha[t][1] = e1 * inv;
        sha[t][2] = e2 * inv;
    }
    __syncthreads();

    // ---- output: one element per thread ----
    {
        int qi = t >> 7;                  // 0..3
        float v = sha[qi][0] * xs[qi][c]
                + sha[qi][1] * xs[qi + 1][c]
                + sha[qi][2] * xs[qi + 2][c];
        out[(size_t)(b * LL + i0 + qi) * DD + c] = v;
    }
}

extern "C" void kernel_launch(void* const* d_in, const int* in_sizes, int n_in,
                              void* d_out, int out_size, void* d_ws, size_t ws_size,
                              hipStream_t stream) {
    const float* x  = (const float*)d_in[0];
    const float* Wt = (const float*)d_in[1];
    const float* Wx = (const float*)d_in[2];
    const float* Wa = (const float*)d_in[3];
    const float* bh = (const float*)d_in[4];
    const float* ba = (const float*)d_in[5];
    float* out = (float*)d_out;

    dim3 grid(BB * (LL / TQ));   // 512 blocks -> 2 blocks/CU
    additive_emission_kernel<<<grid, 512, 0, stream>>>(x, Wt, Wx, Wa, bh, ba, out);
}

// Round 3
// 68.508 us; speedup vs baseline: 1.5091x; 1.0284x over previous
//
#include <hip/hip_runtime.h>
#include <math.h>

#define BB 4
#define LL 512
#define DD 128
#define TQ 4                 // queries per block
#define NROW (TQ + 2)        // 6 staged x rows
#define NACC (NROW + TQ)     // 10 GEMV outputs: 0..5 = k rows, 6..9 = q rows
#define NS 4                 // split-K ways
#define KPT (DD / NS)        // 32 K-values per thread
#define EPSV 1e-8f

__device__ __forceinline__ float fast_tanh(float v) {
    float e = __expf(2.0f * v);
    return 1.0f - 2.0f / (e + 1.0f);
}

__global__ __launch_bounds__(512, 4) void additive_emission_kernel(
    const float* __restrict__ x,   // [B,L,D]
    const float* __restrict__ Wt,  // [D,D] row-major [d_in][d_out]
    const float* __restrict__ Wx,  // [D,D]
    const float* __restrict__ Wa,  // [D]
    const float* __restrict__ bh,  // [D]
    const float* __restrict__ ba,  // [1]  (cancels in softmax -> unused)
    float* __restrict__ out)       // [B,L,D]
{
    __shared__ float xs[NROW][DD];
    __shared__ float part[NS][NACC][DD];
    __shared__ float shbh[DD];
    __shared__ float shwa[DD];
    __shared__ float score[TQ * 3];

    const int t = threadIdx.x;
    const int c = t & 127;            // output column
    const int s = t >> 7;             // split-K slice 0..3 (wave-uniform)
    const int dp0 = s * KPT;
    const int b = blockIdx.x >> 7;    // 128 tiles per batch
    const int tile = blockIdx.x & 127;
    const int i0 = tile * TQ;
    const int jlo = i0 - 1;

    // ---- issue ALL weight loads first; latency overlaps staging+barrier ----
    float wT[KPT], wX[KPT];
    {
        const float* __restrict__ wtp = Wt + (size_t)dp0 * DD + c;
        const float* __restrict__ wxp = Wx + (size_t)dp0 * DD + c;
        #pragma unroll
        for (int k = 0; k < KPT; ++k) {
            wT[k] = wtp[(size_t)k * DD];
            wX[k] = wxp[(size_t)k * DD];
        }
    }

    if (t < DD) { shbh[t] = bh[t]; shwa[t] = Wa[t]; }
    if (t < NROW * (DD / 4)) {        // 192 threads stage 6 x rows as float4
        int r = t >> 5, c4 = t & 31;
        int j = jlo + r;
        float4 v = make_float4(0.f, 0.f, 0.f, 0.f);
        if (j >= 0 && j < LL)
            v = ((const float4*)x)[(size_t)(b * LL + j) * (DD / 4) + c4];
        ((float4*)xs[r])[c4] = v;
    }
    __syncthreads();

    // ---- GEMV: LDS-broadcast x  ×  register weights ----
    float acc[NACC];
    #pragma unroll
    for (int r = 0; r < NACC; ++r) acc[r] = 0.f;

    #pragma unroll
    for (int ch = 0; ch < KPT / 4; ++ch) {
        const int kk = ch * 4;
        float xvv[NROW][4];
        #pragma unroll
        for (int r = 0; r < NROW; ++r) {
            float4 v = ((const float4*)xs[r])[(dp0 + kk) >> 2]; // wave-uniform broadcast
            xvv[r][0] = v.x; xvv[r][1] = v.y; xvv[r][2] = v.z; xvv[r][3] = v.w;
        }
        #pragma unroll
        for (int i = 0; i < 4; ++i) {
            float wx = wX[kk + i];
            float wt = wT[kk + i];
            #pragma unroll
            for (int r = 0; r < NROW; ++r)
                acc[r] += xvv[r][i] * wx;                 // k, 6 rows
            #pragma unroll
            for (int qi = 0; qi < TQ; ++qi)
                acc[NROW + qi] += xvv[qi + 1][i] * wt;    // q, 4 rows
        }
    }
    #pragma unroll
    for (int r = 0; r < NACC; ++r) part[s][r][c] = acc[r];
    __syncthreads();

    // ---- scores: 12 (query, offset) pairs; split-K combine folded in ----
    const int wv = t >> 6;
    const int lane = t & 63;
    for (int p = wv; p < TQ * 3; p += 8) {
        int qi = p / 3, jj = p - qi * 3;
        int j = i0 + qi - 1 + jj;          // global key index
        float sum;
        if (j >= 0 && j < LL) {            // wave-uniform branch
            int r = qi + jj;
            sum = 0.0f;
            #pragma unroll
            for (int u = 0; u < 2; ++u) {
                int d = lane + u * 64;
                float qv = part[0][NROW + qi][d] + part[1][NROW + qi][d]
                         + part[2][NROW + qi][d] + part[3][NROW + qi][d];
                float kv = part[0][r][d] + part[1][r][d]
                         + part[2][r][d] + part[3][r][d];
                sum += fast_tanh(qv + kv + shbh[d]) * shwa[d];
            }
            #pragma unroll
            for (int off = 32; off > 0; off >>= 1)
                sum += __shfl_xor(sum, off, 64);
        } else {
            sum = -1e30f;
        }
        if (lane == 0) score[p] = sum;
    }
    __syncthreads();

    // ---- output: per-thread redundant 3-term softmax + weighted sum ----
    {
        int qi = t >> 7;                   // 0..3 (wave-uniform)
        float s0 = score[qi * 3 + 0], s1 = score[qi * 3 + 1], s2 = score[qi * 3 + 2];
        float m = fmaxf(s0, fmaxf(s1, s2));
        float e0 = (s0 > -1e29f) ? __expf(s0 - m) : 0.0f;
        float e1 = (s1 > -1e29f) ? __expf(s1 - m) : 0.0f;
        float e2 = (s2 > -1e29f) ? __expf(s2 - m) : 0.0f;
        float inv = 1.0f / (e0 + e1 + e2 + EPSV);
        float v = (e0 * xs[qi][c] + e1 * xs[qi + 1][c] + e2 * xs[qi + 2][c]) * inv;
        out[(size_t)(b * LL + i0 + qi) * DD + c] = v;
    }
}

extern "C" void kernel_launch(void* const* d_in, const int* in_sizes, int n_in,
                              void* d_out, int out_size, void* d_ws, size_t ws_size,
                              hipStream_t stream) {
    const float* x  = (const float*)d_in[0];
    const float* Wt = (const float*)d_in[1];
    const float* Wx = (const float*)d_in[2];
    const float* Wa = (const float*)d_in[3];
    const float* bh = (const float*)d_in[4];
    const float* ba = (const float*)d_in[5];
    float* out = (float*)d_out;

    dim3 grid(BB * (LL / TQ));   // 512 blocks -> 2 blocks/CU
    additive_emission_kernel<<<grid, 512, 0, stream>>>(x, Wt, Wx, Wa, bh, ba, out);
}